// Round 9
// baseline (169.275 us; speedup 1.0000x reference)
//
#include <hip/hip_runtime.h>

// Autoregressive LSTM log-prob — fully in-wave MFMA recurrence (no barriers,
// no LDS in the chain). B=4096, L=256, H=32, D=2.
// 2048 WGs x 64 threads (ONE wave, 2 batches). The 16 MFMA N-cols hold the
// 2 batches replicated 8x: n = m + 2*r + 8*s. Lane (n,oct) owns ONE cell
// u = 4*oct + r + 16*s of batch m; its 4 gates sit at tile 2q+s, reg r —
// extracted with a 7-cndmask tree per gate. h-exchange for the next step's
// B-fragment: pack bf16 pair via shfl_xor(2), then 4 ds_bpermute with
// precomputed lane-constant addresses. Gate scales folded into weights
// (i,f,o: -log2e; g: +2log2e); bias (bh+Wi[spin]) added post-extraction.
// Head = 9th MFMA (Wo^T, rows 0,1); raw logits buffered in LDS (off-chain);
// ELU + log-softmax + time reduction post-loop. 8 waves/CU.

typedef __attribute__((ext_vector_type(8))) short bf16x8;
typedef __attribute__((ext_vector_type(4))) float f32x4;

#define LOG2E 1.4426950408889634f
#define LN2   0.6931471805599453f

__device__ __forceinline__ float fexp2(float x) { return __builtin_amdgcn_exp2f(x); }
__device__ __forceinline__ float flog2(float x) { return __builtin_amdgcn_logf(x); }
__device__ __forceinline__ float frcp(float x)  { return __builtin_amdgcn_rcpf(x); }

__device__ __forceinline__ float fsig(float x)   { return frcp(1.f + fexp2(-LOG2E * x)); }
__device__ __forceinline__ float ftanh_(float x) { return 1.f - 2.f * frcp(fexp2(2.f * LOG2E * x) + 1.f); }
__device__ __forceinline__ float felu(float x)   { return x > 0.f ? x : fexp2(LOG2E * x) - 1.f; }

__device__ __forceinline__ unsigned short f2bf(float f) {   // RNE f32->bf16
    unsigned u = __builtin_bit_cast(unsigned, f);
    u = (u + 0x7FFFu + ((u >> 16) & 1u)) >> 16;
    return (unsigned short)u;
}

constexpr int Bsz = 4096;

__global__ __launch_bounds__(64, 2) void lstm_bperm(
    const int*   __restrict__ x,    // [B, 256]
    const float* __restrict__ Wi,   // [2, 128]
    const float* __restrict__ Wh,   // [32, 128]
    const float* __restrict__ bh,   // [128]
    const float* __restrict__ Wo,   // [32, 2]
    const float* __restrict__ bo,   // [2]
    float*       __restrict__ out)  // [B]
{
    const int lane = threadIdx.x & 63;
    const int n    = lane & 15;      // N col
    const int oct  = lane >> 4;
    const int m    = n & 1;          // batch (0/1)
    const int r    = (n >> 1) & 3;   // reg replica
    const int s    = n >> 3;         // unit-half replica
    const int b0   = blockIdx.x * 2;

    __shared__ char   spinT[2][260];    // [batch][t] bytes
    __shared__ float2 Sbuf[256][2];     // raw head logits (S0,S1) per (t,batch)

    // ---- stage spins: 64 lanes x 8 ints ----
    {
        const int row = lane >> 5;
        const int c8  = (lane & 31) * 8;
        const int4* src = reinterpret_cast<const int4*>(x + (b0 + row) * 256 + c8);
        const int4 v0 = src[0], v1 = src[1];
        const int p0 = (v0.x & 1) | ((v0.y & 1) << 8) | ((v0.z & 1) << 16) | ((v0.w & 1) << 24);
        const int p1 = (v1.x & 1) | ((v1.y & 1) << 8) | ((v1.z & 1) << 16) | ((v1.w & 1) << 24);
        *reinterpret_cast<int*>(&spinT[row][c8])     = p0;
        *reinterpret_cast<int*>(&spinT[row][c8 + 4]) = p1;
    }
    // single wave: DS pipe is in-order, no barrier needed anywhere.

    // ---- A-fragments: tile 2q+sx covers gate q, units 16sx..16sx+15.
    // Row n <-> gate-col 32q + 16sx + n; k-slot j <-> unit 8oct+j.
    bf16x8 wfrag[8];
#pragma unroll
    for (int q = 0; q < 4; ++q) {
        const float gs = (q == 2) ? 2.f * LOG2E : -LOG2E;
#pragma unroll
        for (int sx = 0; sx < 2; ++sx)
#pragma unroll
            for (int j = 0; j < 8; ++j)
                wfrag[2 * q + sx][j] =
                    (short)f2bf(gs * Wh[(8 * oct + j) * 128 + 32 * q + 16 * sx + n]);
    }
    bf16x8 wofrag;   // head: Wo^T in rows 0,1
#pragma unroll
    for (int j = 0; j < 8; ++j)
        wofrag[j] = (n < 2) ? (short)f2bf(Wo[(8 * oct + j) * 2 + n]) : (short)0;

    // ---- this lane's cell + scaled biases ----
    const int u = 4 * oct + r + 16 * s;
    float bv0[4], bvd[4];
#pragma unroll
    for (int q = 0; q < 4; ++q) {
        const float gs = (q == 2) ? 2.f * LOG2E : -LOG2E;
        const int c0 = 32 * q + u;
        bv0[q] = gs * (bh[c0] + Wi[c0]);
        bvd[q] = gs * (Wi[128 + c0] - Wi[c0]);
    }
    const float bo0 = bo[0], bo1 = bo[1];

    // ---- bpermute addresses (lane constants): dword d of the B-frag holds
    // units (8oct+2d, 8oct+2d+1) of batch m; its canonical producer lane is
    // m + 4*(d&1) + 8*(oct>>1) + 16*(2*(oct&1) + (d>>1)).
    int badr[4];
#pragma unroll
    for (int d = 0; d < 4; ++d)
        badr[d] = 4 * (m + 4 * (d & 1) + 8 * (oct >> 1) + 16 * (2 * (oct & 1) + (d >> 1)));

    const bool rodd = (r & 1) != 0;
    const bool rhi  = (r & 2) != 0;
    const bool shi  = (s != 0);

    // pack own h + partner (lane^2) into a dword, gather B-frag via bpermute
    auto exchange = [&](float h) -> bf16x8 {
        const int hv = (int)f2bf(h);
        const int ot = __shfl_xor(hv, 2, 64);
        const int lo = rodd ? ot : hv;
        const int hi = rodd ? hv : ot;
        const int dw = lo | (hi << 16);
        union { bf16x8 v; int i[4]; } hf;
#pragma unroll
        for (int d = 0; d < 4; ++d)
            hf.i[d] = __builtin_amdgcn_ds_bpermute(badr[d], dw);
        return hf.v;
    };

    // select reg r from tile pair (a = tile s=0, b = tile s=1)
    auto ex = [&](const f32x4& a, const f32x4& b) -> float {
        const float a01 = rodd ? a[1] : a[0];
        const float a23 = rodd ? a[3] : a[2];
        const float av  = rhi ? a23 : a01;
        const float b01 = rodd ? b[1] : b[0];
        const float b23 = rodd ? b[3] : b[2];
        const float bv  = rhi ? b23 : b01;
        return shi ? bv : av;
    };

    // ---- peel t=0: input zeros, h=c=0 -> gates = bh ----
    float c = fsig(bh[u]) * ftanh_(bh[64 + u]);
    bf16x8 hfrag = exchange(fsig(bh[96 + u]) * ftanh_(c));
    float spf = (float)spinT[m][0];

    const f32x4 zero4 = { 0.f, 0.f, 0.f, 0.f };

    for (int t = 1; t < 256; ++t) {
        // biases for step t's gates (spin_{t-1}) — off the MFMA chain
        float bias[4];
#pragma unroll
        for (int q = 0; q < 4; ++q) bias[q] = fmaf(spf, bvd[q], bv0[q]);

        f32x4 acc[8];
#pragma unroll
        for (int tt = 0; tt < 8; ++tt)
            acc[tt] = __builtin_amdgcn_mfma_f32_16x16x32_bf16(wfrag[tt], hfrag, zero4, 0, 0, 0);
        const f32x4 hacc =
            __builtin_amdgcn_mfma_f32_16x16x32_bf16(wofrag, hfrag, zero4, 0, 0, 0);

        if (lane < 2) Sbuf[t - 1][lane] = make_float2(hacc[0], hacc[1]);
        const float spn = (float)spinT[m][t];   // prefetch next spin

        const float g0 = ex(acc[0], acc[1]) + bias[0];
        const float g1 = ex(acc[2], acc[3]) + bias[1];
        const float g2 = ex(acc[4], acc[5]) + bias[2];
        const float g3 = ex(acc[6], acc[7]) + bias[3];

        // cell update: e_i=e^{-i}, e_f=e^{-f}, e_g=e^{2g}, e_o=e^{-o}
        float h;
        {
            const float ei = fexp2(g0), ef = fexp2(g1);
            const float eg = fexp2(g2), eo = fexp2(g3);
            const float P = (1.f + ei) * (1.f + eg);
            const float Q = 1.f + ef;
            const float R = frcp(P * Q);
            const float gf  = P * R;
            const float igt = (eg - 1.f) * Q * R;
            c = fmaf(gf, c, igt);
            const float ec = fexp2(2.f * LOG2E * c);
            h = (ec - 1.f) * frcp((1.f + eo) * (1.f + ec));
        }
        hfrag = exchange(h);
        spf = spn;
    }

    // ---- tail: head logits of step 255 ----
    {
        const f32x4 hacc =
            __builtin_amdgcn_mfma_f32_16x16x32_bf16(wofrag, hfrag, zero4, 0, 0, 0);
        if (lane < 2) Sbuf[255][lane] = make_float2(hacc[0], hacc[1]);
    }

    // ---- post phase: ELU + log-softmax + time reduction (in-wave) ----
    {
        const int m2 = lane & 1;
        const int t0 = (lane >> 1) * 8;
        float lp = 0.f;
#pragma unroll
        for (int i = 0; i < 8; ++i) {
            const int t = t0 + i;
            const float2 sv = Sbuf[t][m2];
            const int sp = spinT[m2][t];
            const float o0 = felu(sv.x + bo0);
            const float o1 = felu(sv.y + bo1);
            const float mx = fmaxf(o0, o1), mn = fminf(o0, o1);
            const float lse = mx + LN2 * flog2(1.f + fexp2(LOG2E * (mn - mx)));
            lp += (sp ? o1 : o0) - lse;
        }
        lp += __shfl_xor(lp, 2, 64);
        lp += __shfl_xor(lp, 4, 64);
        lp += __shfl_xor(lp, 8, 64);
        lp += __shfl_xor(lp, 16, 64);
        lp += __shfl_xor(lp, 32, 64);
        if (lane < 2) out[b0 + lane] = 0.5f * lp;
    }
}

extern "C" void kernel_launch(void* const* d_in, const int* in_sizes, int n_in,
                              void* d_out, int out_size, void* d_ws, size_t ws_size,
                              hipStream_t stream) {
    const int*   x  = (const int*)d_in[0];
    const float* Wi = (const float*)d_in[1];
    const float* Wh = (const float*)d_in[2];
    const float* bh = (const float*)d_in[3];
    const float* Wo = (const float*)d_in[4];
    const float* bo = (const float*)d_in[5];
    float* out = (float*)d_out;

    lstm_bperm<<<dim3(Bsz / 2), dim3(64), 0, stream>>>(x, Wi, Wh, bh, Wo, bo, out);
}

// Round 10
// 136.939 us; speedup vs baseline: 1.2361x; 1.2361x over previous
//
#include <hip/hip_runtime.h>

// Autoregressive LSTM log-prob via MFMA, 8-wave split-cell (R7 structure,
// trimmed). B=4096, L=256, H=32, D=2. 256 WGs x 512 threads, 16 batches/WG.
// gates^T = Wh^T @ h^T; wave w (rot=w&3, half=w>>2) computes the 4 gate
// tiles of its unit half, row-rotated so its ONE cell/lane sits in acc reg 0.
// Trims vs R7: 2-step unroll (static dbuf indices), 80B-stride hbuf
// (aligned ds_read_b128, free 2-way banking), head MFMA round-robined
// across waves by (t-1)&7 (no per-step straggler), spins via one
// ds_read_u16 per 2 steps prefetched a pair ahead, combined-rcp cell
// (7 transcendentals). One barrier per step. Logits raw in LDS; ELU +
// log-softmax + time reduction post-loop.

typedef __attribute__((ext_vector_type(8))) short bf16x8;
typedef __attribute__((ext_vector_type(4))) float f32x4;

#define LOG2E 1.4426950408889634f
#define LN2   0.6931471805599453f

__device__ __forceinline__ float fexp2(float x) { return __builtin_amdgcn_exp2f(x); }
__device__ __forceinline__ float flog2(float x) { return __builtin_amdgcn_logf(x); }
__device__ __forceinline__ float frcp(float x)  { return __builtin_amdgcn_rcpf(x); }

__device__ __forceinline__ float fsig(float x)   { return frcp(1.f + fexp2(-LOG2E * x)); }
__device__ __forceinline__ float ftanh_(float x) { return 1.f - 2.f * frcp(fexp2(2.f * LOG2E * x) + 1.f); }
__device__ __forceinline__ float felu(float x)   { return x > 0.f ? x : fexp2(LOG2E * x) - 1.f; }

__device__ __forceinline__ unsigned short f2bf(float f) {   // RNE f32->bf16
    unsigned u = __builtin_bit_cast(unsigned, f);
    u = (u + 0x7FFFu + ((u >> 16) & 1u)) >> 16;
    return (unsigned short)u;
}

constexpr int Bsz = 4096;

__global__ __launch_bounds__(512, 2) void lstm_r10(
    const int*   __restrict__ x,    // [B, 256]
    const float* __restrict__ Wi,   // [2, 128]
    const float* __restrict__ Wh,   // [32, 128]
    const float* __restrict__ bh,   // [128]
    const float* __restrict__ Wo,   // [32, 2]
    const float* __restrict__ bo,   // [2]
    float*       __restrict__ out)  // [B]
{
    const int tid  = threadIdx.x;
    const int w    = tid >> 6;      // wave 0..7
    const int lane = tid & 63;
    const int m    = lane & 15;     // batch column
    const int oct  = lane >> 4;
    const int rot  = w & 3;         // gate-row rotation
    const int half = w >> 2;        // unit half
    const int b0   = blockIdx.x * 16;

    __shared__ char   spinT[16][260];     // [batch][t] bytes, padded row
    __shared__ float2 Sbuf[256][16];      // raw logits (S0,S1) per (t,batch)
    __shared__ short  hbuf[2][16][40];    // h dbuf, row stride 80 B (16B aligned)
    __shared__ float  red[8][16];

    // ---- stage spins: 512 threads x 8 ints ----
    {
        const int bl = tid >> 5;
        const int c8 = (tid & 31) * 8;
        const int4* src = reinterpret_cast<const int4*>(x + (b0 + bl) * 256 + c8);
        const int4 v0 = src[0], v1 = src[1];
        const int p0 = (v0.x & 1) | ((v0.y & 1) << 8) | ((v0.z & 1) << 16) | ((v0.w & 1) << 24);
        const int p1 = (v1.x & 1) | ((v1.y & 1) << 8) | ((v1.z & 1) << 16) | ((v1.w & 1) << 24);
        *reinterpret_cast<int*>(&spinT[bl][c8])     = p0;
        *reinterpret_cast<int*>(&spinT[bl][c8 + 4]) = p1;
    }

    // ---- weight A-frags: 4 tiles (gate q, unit-half), rows rotated by rot
    bf16x8 wfrag[4];
#pragma unroll
    for (int q = 0; q < 4; ++q) {
        const float gs = (q == 2) ? 2.f * LOG2E : -LOG2E;
        const int colg = 32 * q + 16 * half + ((m + rot) & 15);
#pragma unroll
        for (int j = 0; j < 8; ++j)
            wfrag[q][j] = (short)f2bf(gs * Wh[(oct * 8 + j) * 128 + colg]);
    }
    bf16x8 wofragA;   // head: Wo^T padded to 16 rows (all waves hold it)
#pragma unroll
    for (int j = 0; j < 8; ++j)
        wofragA[j] = (m < 2) ? (short)f2bf(Wo[(oct * 8 + j) * 2 + m]) : (short)0;

    // ---- this lane's cell + scaled biases ----
    const int ucell = 4 * oct + rot + 16 * half;
    float bv0[4], bvd[4];
#pragma unroll
    for (int q = 0; q < 4; ++q) {
        const float gs = (q == 2) ? 2.f * LOG2E : -LOG2E;
        const int c0 = 32 * q + ucell;
        bv0[q] = gs * (bh[c0] + Wi[c0]);
        bvd[q] = gs * (Wi[128 + c0] - Wi[c0]);
    }
    const float bo0 = bo[0], bo1 = bo[1];

    // ---- peel t=0: input zeros, h=c=0 -> gates = bh ----
    float c = fsig(bh[ucell]) * ftanh_(bh[64 + ucell]);
    hbuf[0][m][ucell] = (short)f2bf(fsig(bh[96 + ucell]) * ftanh_(c));
    __syncthreads();

    const f32x4 zero4 = { 0.f, 0.f, 0.f, 0.f };
    f32x4 ccq[4] = { zero4, zero4, zero4, zero4 };   // persistent C quads

    // one step; rb/wb are compile-time at each call site -> static addresses
    auto step = [&](const int t, const int rb, const int wb, const float spf) {
        const bf16x8 hfrag =
            *reinterpret_cast<const bf16x8*>(&hbuf[rb][m][8 * oct]);

        // bias (bh + Wi[spin_{t-1}]) into C reg 0 — off the MFMA chain
#pragma unroll
        for (int q = 0; q < 4; ++q) ccq[q][0] = fmaf(spf, bvd[q], bv0[q]);

        f32x4 acc[4];
#pragma unroll
        for (int q = 0; q < 4; ++q)
            acc[q] = __builtin_amdgcn_mfma_f32_16x16x32_bf16(wfrag[q], hfrag, ccq[q], 0, 0, 0);

        // head logits of step t-1: round-robin over waves (no fixed straggler)
        if (((t - 1) & 7) == w) {
            const f32x4 hacc =
                __builtin_amdgcn_mfma_f32_16x16x32_bf16(wofragA, hfrag, zero4, 0, 0, 0);
            if (oct == 0) Sbuf[t - 1][m] = make_float2(hacc[0], hacc[1]);
        }

        // cell update (gates in acc[q][0]); e_i=e^{-i}, e_f=e^{-f},
        // e_g=e^{2g}, e_o=e^{-o}; combined reciprocal saves one rcp.
        {
            const float ei = fexp2(acc[0][0]), ef = fexp2(acc[1][0]);
            const float eg = fexp2(acc[2][0]), eo = fexp2(acc[3][0]);
            const float P = (1.f + ei) * (1.f + eg);
            const float Q = 1.f + ef;
            const float R = frcp(P * Q);
            const float gf  = P * R;                 // 1/(1+ef)
            const float igt = (eg - 1.f) * Q * R;    // sig(i)*tanh(g)
            c = fmaf(gf, c, igt);
            const float ec = fexp2(2.f * LOG2E * c);
            const float h  = (ec - 1.f) * frcp((1.f + eo) * (1.f + ec));
            hbuf[wb][m][ucell] = (short)f2bf(h);
        }
        __syncthreads();   // h_t visible to all waves
    };

    // spins for pair (tb, tb+1) = bytes (tb-1, tb), prefetched a pair ahead
    unsigned sp2 = *reinterpret_cast<const unsigned short*>(&spinT[m][0]);
    for (int tb = 1; tb < 255; tb += 2) {
        const unsigned sp2n =
            *reinterpret_cast<const unsigned short*>(&spinT[m][tb + 1]);
        step(tb,     0, 1, (float)(sp2 & 0xFFu));
        step(tb + 1, 1, 0, (float)(sp2 >> 8));
        sp2 = sp2n;
    }
    step(255, 0, 1, (float)(sp2 & 0xFFu));   // uses spin 254

    // ---- tail: head logits of step 255 (h_255 in hbuf[1]) ----
    if (w == 7) {
        const bf16x8 hfrag = *reinterpret_cast<const bf16x8*>(&hbuf[1][m][8 * oct]);
        const f32x4 hacc =
            __builtin_amdgcn_mfma_f32_16x16x32_bf16(wofragA, hfrag, zero4, 0, 0, 0);
        if (oct == 0) Sbuf[255][m] = make_float2(hacc[0], hacc[1]);
    }
    __syncthreads();

    // ---- post phase: ELU + log-softmax + sum over t, 32 time-chunks ----
    float lp = 0.f;
    {
        const int t0 = (w * 4 + oct) * 8;
#pragma unroll
        for (int i = 0; i < 8; ++i) {
            const int t = t0 + i;
            const float2 sv = Sbuf[t][m];
            const int sp = spinT[m][t];
            const float o0 = felu(sv.x + bo0);
            const float o1 = felu(sv.y + bo1);
            const float mx = fmaxf(o0, o1), mn = fminf(o0, o1);
            const float lse = mx + LN2 * flog2(1.f + fexp2(LOG2E * (mn - mx)));
            lp += (sp ? o1 : o0) - lse;
        }
    }
    lp += __shfl_xor(lp, 16, 64);   // reduce over oct
    lp += __shfl_xor(lp, 32, 64);
    if (lane < 16) red[w][lane] = lp;
    __syncthreads();
    if (tid < 16) {
        float s = 0.f;
#pragma unroll
        for (int ww = 0; ww < 8; ++ww) s += red[ww][tid];
        out[b0 + tid] = 0.5f * s;
    }
}

extern "C" void kernel_launch(void* const* d_in, const int* in_sizes, int n_in,
                              void* d_out, int out_size, void* d_ws, size_t ws_size,
                              hipStream_t stream) {
    const int*   x  = (const int*)d_in[0];
    const float* Wi = (const float*)d_in[1];
    const float* Wh = (const float*)d_in[2];
    const float* bh = (const float*)d_in[3];
    const float* Wo = (const float*)d_in[4];
    const float* bo = (const float*)d_in[5];
    float* out = (float*)d_out;

    lstm_r10<<<dim3(Bsz / 16), dim3(512), 0, stream>>>(x, Wi, Wh, bh, Wo, bo, out);
}